// Round 6
// baseline (382.426 us; speedup 1.0000x reference)
//
#include <hip/hip_runtime.h>
#include <hip/hip_cooperative_groups.h>

namespace cg = cooperative_groups;

#define KN 1000000
#define NCOLS 70400
#define NBLK 512
#define NTHR 256
#define TOT (NBLK * NTHR)

// Order-preserving float<->uint encoding for atomicMax, biased so that
// encode(SENTINEL) == 0 -> zero-initialized slots decode to SENTINEL.
__device__ __forceinline__ unsigned encodeF(float f) {
    unsigned b = __float_as_uint(f);
    return (b & 0x80000000u) ? ~b : (b | 0x80000000u);
}
__device__ __forceinline__ float decodeF(unsigned e) {
    unsigned b = (e & 0x80000000u) ? (e & 0x7fffffffu) : ~e;
    return __uint_as_float(b);
}
// encodeF(-9999999.0f): bits 0xCB18967F -> ~ = 0x34E76980
#define ENC_SENT 0x34E76980u

#define RELU(x) fmaxf((x), 0.0f)

#define L1(j) const float h1_##j = RELU(fmaf(W1[4*(j)+0], x0, fmaf(W1[4*(j)+1], x1, \
                        fmaf(W1[4*(j)+2], x2, fmaf(W1[4*(j)+3], x3, b1[(j)])))));

#define DOT18(j) \
 fmaf(W2[(j)*18+ 0],h1_0 ,fmaf(W2[(j)*18+ 1],h1_1 ,fmaf(W2[(j)*18+ 2],h1_2 ,fmaf(W2[(j)*18+ 3],h1_3 , \
 fmaf(W2[(j)*18+ 4],h1_4 ,fmaf(W2[(j)*18+ 5],h1_5 ,fmaf(W2[(j)*18+ 6],h1_6 ,fmaf(W2[(j)*18+ 7],h1_7 , \
 fmaf(W2[(j)*18+ 8],h1_8 ,fmaf(W2[(j)*18+ 9],h1_9 ,fmaf(W2[(j)*18+10],h1_10,fmaf(W2[(j)*18+11],h1_11, \
 fmaf(W2[(j)*18+12],h1_12,fmaf(W2[(j)*18+13],h1_13,fmaf(W2[(j)*18+14],h1_14,fmaf(W2[(j)*18+15],h1_15, \
 fmaf(W2[(j)*18+16],h1_16,fmaf(W2[(j)*18+17],h1_17, b2[(j)]))))))))))))))))))

#define L2(j) const float h2_##j = RELU(DOT18(j));

#define DOT36(j) \
 fmaf(W3[(j)*36+ 0],h2_0 ,fmaf(W3[(j)*36+ 1],h2_1 ,fmaf(W3[(j)*36+ 2],h2_2 ,fmaf(W3[(j)*36+ 3],h2_3 , \
 fmaf(W3[(j)*36+ 4],h2_4 ,fmaf(W3[(j)*36+ 5],h2_5 ,fmaf(W3[(j)*36+ 6],h2_6 ,fmaf(W3[(j)*36+ 7],h2_7 , \
 fmaf(W3[(j)*36+ 8],h2_8 ,fmaf(W3[(j)*36+ 9],h2_9 ,fmaf(W3[(j)*36+10],h2_10,fmaf(W3[(j)*36+11],h2_11, \
 fmaf(W3[(j)*36+12],h2_12,fmaf(W3[(j)*36+13],h2_13,fmaf(W3[(j)*36+14],h2_14,fmaf(W3[(j)*36+15],h2_15, \
 fmaf(W3[(j)*36+16],h2_16,fmaf(W3[(j)*36+17],h2_17,fmaf(W3[(j)*36+18],h2_18,fmaf(W3[(j)*36+19],h2_19, \
 fmaf(W3[(j)*36+20],h2_20,fmaf(W3[(j)*36+21],h2_21,fmaf(W3[(j)*36+22],h2_22,fmaf(W3[(j)*36+23],h2_23, \
 fmaf(W3[(j)*36+24],h2_24,fmaf(W3[(j)*36+25],h2_25,fmaf(W3[(j)*36+26],h2_26,fmaf(W3[(j)*36+27],h2_27, \
 fmaf(W3[(j)*36+28],h2_28,fmaf(W3[(j)*36+29],h2_29,fmaf(W3[(j)*36+30],h2_30,fmaf(W3[(j)*36+31],h2_31, \
 fmaf(W3[(j)*36+32],h2_32,fmaf(W3[(j)*36+33],h2_33,fmaf(W3[(j)*36+34],h2_34,fmaf(W3[(j)*36+35],h2_35, \
 b3[(j)]))))))))))))))))))))))))))))))))))))

#define L34(j) v = fmaf(W4[(j)], RELU(DOT36(j)), v);

// Whole straight-line MLP for element index `kk`; leaves result in `v`, col in `col`.
#define MLP_COMPUTE(kk)                                                        \
    const float x0 = x[0 * KN + (kk)];                                         \
    const float x1 = x[1 * KN + (kk)];                                         \
    const float x2 = x[2 * KN + (kk)];                                         \
    const float x3 = x[3 * KN + (kk)];                                         \
    L1(0)  L1(1)  L1(2)  L1(3)  L1(4)  L1(5)  L1(6)  L1(7)  L1(8)             \
    L1(9)  L1(10) L1(11) L1(12) L1(13) L1(14) L1(15) L1(16) L1(17)            \
    L2(0)  L2(1)  L2(2)  L2(3)  L2(4)  L2(5)  L2(6)  L2(7)  L2(8)             \
    L2(9)  L2(10) L2(11) L2(12) L2(13) L2(14) L2(15) L2(16) L2(17)            \
    L2(18) L2(19) L2(20) L2(21) L2(22) L2(23) L2(24) L2(25) L2(26)            \
    L2(27) L2(28) L2(29) L2(30) L2(31) L2(32) L2(33) L2(34) L2(35)            \
    float v = b4[0];                                                           \
    L34(0)  L34(1)  L34(2)  L34(3)  L34(4)  L34(5)  L34(6)  L34(7)  L34(8)    \
    L34(9)  L34(10) L34(11) L34(12) L34(13) L34(14) L34(15) L34(16) L34(17)   \
    L34(18) L34(19) L34(20) L34(21) L34(22) L34(23) L34(24) L34(25) L34(26)   \
    L34(27) L34(28) L34(29) L34(30) L34(31) L34(32) L34(33) L34(34) L34(35)   \
    const int col = ((const int2*)tidx)[(kk)].y;

// ---------------- fused cooperative kernel: init -> mlp/scatter -> decode ----
// amdgpu_waves_per_eu(4,4) pins the allocator to exactly 4 waves/EU: a fixed
// 128-VGPR budget with NO incentive to shrink registers for occupancy (R3-R5
// all came out VGPR_Count=28 with h-state in scratch; that was the ~90us).
__global__ __launch_bounds__(NTHR)
__attribute__((amdgpu_waves_per_eu(4, 4)))
void fused_kernel(const float* __restrict__ x, const int* __restrict__ tidx,
                  const float* __restrict__ W1, const float* __restrict__ b1,
                  const float* __restrict__ W2, const float* __restrict__ b2,
                  const float* __restrict__ W3, const float* __restrict__ b3,
                  const float* __restrict__ W4, const float* __restrict__ b4,
                  unsigned* __restrict__ outU, int out_size)
{
    cg::grid_group grid = cg::this_grid();
    const int tid = blockIdx.x * blockDim.x + threadIdx.x;

    // phase 1: init slots to encode(SENTINEL)-bias == 0
    for (int i = tid; i < NCOLS; i += TOT) outU[i] = 0u;
    grid.sync();

    // phase 2: MLP + column scatter-max (row index irrelevant after row-max)
    for (int k = tid; k < KN; k += TOT) {
        MLP_COMPUTE(k)
        atomicMax(&outU[col], encodeF(v) - ENC_SENT);
    }
    grid.sync();

    // phase 3: decode in place + flag
    for (int i = tid; i < out_size; i += TOT) {
        float r = (i < NCOLS) ? decodeF(outU[i] + ENC_SENT) : 1.0f;
        ((float*)outU)[i] = r;
    }
}

// ---------------- fallback path (3 plain launches) ---------------------------
__global__ __launch_bounds__(256) void init_kernel(unsigned* __restrict__ outU) {
    int gid = blockIdx.x * blockDim.x + threadIdx.x;
    if (gid < NCOLS) outU[gid] = 0u;
}

__global__ __launch_bounds__(256)
__attribute__((amdgpu_waves_per_eu(4, 4)))
void mlp_scatter_kernel(const float* __restrict__ x, const int* __restrict__ tidx,
                        const float* __restrict__ W1, const float* __restrict__ b1,
                        const float* __restrict__ W2, const float* __restrict__ b2,
                        const float* __restrict__ W3, const float* __restrict__ b3,
                        const float* __restrict__ W4, const float* __restrict__ b4,
                        unsigned* __restrict__ outU)
{
    const int k = blockIdx.x * blockDim.x + threadIdx.x;
    if (k >= KN) return;
    MLP_COMPUTE(k)
    atomicMax(&outU[col], encodeF(v) - ENC_SENT);
}

__global__ __launch_bounds__(256) void decode_kernel(unsigned* __restrict__ outU,
                                                     int out_size) {
    int gid = blockIdx.x * blockDim.x + threadIdx.x;
    if (gid < out_size) {
        float r = (gid < NCOLS) ? decodeF(outU[gid] + ENC_SENT) : 1.0f;
        ((float*)outU)[gid] = r;
    }
}

extern "C" void kernel_launch(void* const* d_in, const int* in_sizes, int n_in,
                              void* d_out, int out_size, void* d_ws, size_t ws_size,
                              hipStream_t stream) {
    const float* x    = (const float*)d_in[0];   // (1,4,1,K)
    const int*   tidx = (const int*)d_in[1];     // (K,2)
    const float* W1 = (const float*)d_in[2];
    const float* b1 = (const float*)d_in[3];
    const float* W2 = (const float*)d_in[4];
    const float* b2 = (const float*)d_in[5];
    const float* W3 = (const float*)d_in[6];
    const float* b3 = (const float*)d_in[7];
    const float* W4 = (const float*)d_in[8];
    const float* b4 = (const float*)d_in[9];
    unsigned* outU = (unsigned*)d_out;

    void* args[] = { (void*)&x, (void*)&tidx,
                     (void*)&W1, (void*)&b1, (void*)&W2, (void*)&b2,
                     (void*)&W3, (void*)&b3, (void*)&W4, (void*)&b4,
                     (void*)&outU, (void*)&out_size };

    hipError_t err = hipLaunchCooperativeKernel((const void*)fused_kernel,
                                                dim3(NBLK), dim3(NTHR),
                                                args, 0, stream);
    if (err != hipSuccess) {
        // deterministic fallback: same work, 3 dispatches
        init_kernel<<<(NCOLS + 255) / 256, 256, 0, stream>>>(outU);
        mlp_scatter_kernel<<<(KN + 255) / 256, 256, 0, stream>>>(
            x, tidx, W1, b1, W2, b2, W3, b3, W4, b4, outU);
        decode_kernel<<<(out_size + 255) / 256, 256, 0, stream>>>(outU, out_size);
    }
}

// Round 7
// 164.418 us; speedup vs baseline: 2.3259x; 2.3259x over previous
//
#include <hip/hip_runtime.h>

#define KN 1000000
#define NCOLS 70400

// Order-preserving float<->uint encoding for atomicMax, biased so that
// encode(SENTINEL) == 0 -> zero-initialized slots decode to SENTINEL.
__device__ __forceinline__ unsigned encodeF(float f) {
    unsigned b = __float_as_uint(f);
    return (b & 0x80000000u) ? ~b : (b | 0x80000000u);
}
__device__ __forceinline__ float decodeF(unsigned e) {
    unsigned b = (e & 0x80000000u) ? (e & 0x7fffffffu) : ~e;
    return __uint_as_float(b);
}
// encodeF(-9999999.0f): bits 0xCB18967F -> ~ = 0x34E76980
#define ENC_SENT 0x34E76980u

#define RELU(x) fmaxf((x), 0.0f)
#define CAT(a, b) a##b

// ---- 2 elements (a,b) per thread: one weight fetch (wave-uniform s_load)
// ---- feeds 128 element-lanes' FMAs -> halves the fetch-pipe cost that has
// ---- pinned every round at ~90us. 4 independent FMA chains (2j x 2elem).

#define L1E(j) \
  const float h1a_##j = RELU(fmaf(W1[4*(j)+0], xa0, fmaf(W1[4*(j)+1], xa1, \
                        fmaf(W1[4*(j)+2], xa2, fmaf(W1[4*(j)+3], xa3, b1[(j)]))))); \
  const float h1b_##j = RELU(fmaf(W1[4*(j)+0], xb0, fmaf(W1[4*(j)+1], xb1, \
                        fmaf(W1[4*(j)+2], xb2, fmaf(W1[4*(j)+3], xb3, b1[(j)])))));

#define A4(W, N, i, j0, j1, ha, hb) \
  s00 = fmaf(W[(j0)*(N)+(i)], CAT(ha, i), s00); \
  s01 = fmaf(W[(j1)*(N)+(i)], CAT(ha, i), s01); \
  s10 = fmaf(W[(j0)*(N)+(i)], CAT(hb, i), s10); \
  s11 = fmaf(W[(j1)*(N)+(i)], CAT(hb, i), s11);

#define AC18(j0, j1, ha, hb) \
  A4(W2,18, 0,j0,j1,ha,hb) A4(W2,18, 1,j0,j1,ha,hb) A4(W2,18, 2,j0,j1,ha,hb) \
  A4(W2,18, 3,j0,j1,ha,hb) A4(W2,18, 4,j0,j1,ha,hb) A4(W2,18, 5,j0,j1,ha,hb) \
  A4(W2,18, 6,j0,j1,ha,hb) A4(W2,18, 7,j0,j1,ha,hb) A4(W2,18, 8,j0,j1,ha,hb) \
  A4(W2,18, 9,j0,j1,ha,hb) A4(W2,18,10,j0,j1,ha,hb) A4(W2,18,11,j0,j1,ha,hb) \
  A4(W2,18,12,j0,j1,ha,hb) A4(W2,18,13,j0,j1,ha,hb) A4(W2,18,14,j0,j1,ha,hb) \
  A4(W2,18,15,j0,j1,ha,hb) A4(W2,18,16,j0,j1,ha,hb) A4(W2,18,17,j0,j1,ha,hb)

#define AC36(j0, j1, ha, hb) \
  A4(W3,36, 0,j0,j1,ha,hb) A4(W3,36, 1,j0,j1,ha,hb) A4(W3,36, 2,j0,j1,ha,hb) \
  A4(W3,36, 3,j0,j1,ha,hb) A4(W3,36, 4,j0,j1,ha,hb) A4(W3,36, 5,j0,j1,ha,hb) \
  A4(W3,36, 6,j0,j1,ha,hb) A4(W3,36, 7,j0,j1,ha,hb) A4(W3,36, 8,j0,j1,ha,hb) \
  A4(W3,36, 9,j0,j1,ha,hb) A4(W3,36,10,j0,j1,ha,hb) A4(W3,36,11,j0,j1,ha,hb) \
  A4(W3,36,12,j0,j1,ha,hb) A4(W3,36,13,j0,j1,ha,hb) A4(W3,36,14,j0,j1,ha,hb) \
  A4(W3,36,15,j0,j1,ha,hb) A4(W3,36,16,j0,j1,ha,hb) A4(W3,36,17,j0,j1,ha,hb) \
  A4(W3,36,18,j0,j1,ha,hb) A4(W3,36,19,j0,j1,ha,hb) A4(W3,36,20,j0,j1,ha,hb) \
  A4(W3,36,21,j0,j1,ha,hb) A4(W3,36,22,j0,j1,ha,hb) A4(W3,36,23,j0,j1,ha,hb) \
  A4(W3,36,24,j0,j1,ha,hb) A4(W3,36,25,j0,j1,ha,hb) A4(W3,36,26,j0,j1,ha,hb) \
  A4(W3,36,27,j0,j1,ha,hb) A4(W3,36,28,j0,j1,ha,hb) A4(W3,36,29,j0,j1,ha,hb) \
  A4(W3,36,30,j0,j1,ha,hb) A4(W3,36,31,j0,j1,ha,hb) A4(W3,36,32,j0,j1,ha,hb) \
  A4(W3,36,33,j0,j1,ha,hb) A4(W3,36,34,j0,j1,ha,hb) A4(W3,36,35,j0,j1,ha,hb)

#define L2P(j0, j1) \
  float h2a_##j0, h2a_##j1, h2b_##j0, h2b_##j1; \
  { float s00 = b2[(j0)], s01 = b2[(j1)], s10 = b2[(j0)], s11 = b2[(j1)]; \
    AC18(j0, j1, h1a_, h1b_) \
    h2a_##j0 = RELU(s00); h2a_##j1 = RELU(s01); \
    h2b_##j0 = RELU(s10); h2b_##j1 = RELU(s11); }

#define L34P(j0, j1) \
  { float s00 = b3[(j0)], s01 = b3[(j1)], s10 = b3[(j0)], s11 = b3[(j1)]; \
    AC36(j0, j1, h2a_, h2b_) \
    va = fmaf(W4[(j0)], RELU(s00), va); va = fmaf(W4[(j1)], RELU(s01), va); \
    vb = fmaf(W4[(j0)], RELU(s10), vb); vb = fmaf(W4[(j1)], RELU(s11), vb); }

__global__ __launch_bounds__(256)
__attribute__((amdgpu_waves_per_eu(4, 4)))   // pin: fixed 128-VGPR budget, no
                                             // occupancy-chasing spills (R6
                                             // proved this lever moves VGPRs)
void mlp_scatter_kernel(const float* __restrict__ x, const int* __restrict__ tidx,
                        const float* __restrict__ W1, const float* __restrict__ b1,
                        const float* __restrict__ W2, const float* __restrict__ b2,
                        const float* __restrict__ W3, const float* __restrict__ b3,
                        const float* __restrict__ W4, const float* __restrict__ b4,
                        unsigned* __restrict__ outU)
{
    const int k0 = (blockIdx.x * blockDim.x + threadIdx.x) * 2;
    if (k0 >= KN) return;

    const float2 xv0 = *(const float2*)(x + 0 * KN + k0);
    const float2 xv1 = *(const float2*)(x + 1 * KN + k0);
    const float2 xv2 = *(const float2*)(x + 2 * KN + k0);
    const float2 xv3 = *(const float2*)(x + 3 * KN + k0);
    const float xa0 = xv0.x, xa1 = xv1.x, xa2 = xv2.x, xa3 = xv3.x;
    const float xb0 = xv0.y, xb1 = xv1.y, xb2 = xv2.y, xb3 = xv3.y;

    L1E(0)  L1E(1)  L1E(2)  L1E(3)  L1E(4)  L1E(5)  L1E(6)  L1E(7)  L1E(8)
    L1E(9)  L1E(10) L1E(11) L1E(12) L1E(13) L1E(14) L1E(15) L1E(16) L1E(17)

    L2P(0, 1)   L2P(2, 3)   L2P(4, 5)   L2P(6, 7)   L2P(8, 9)
    L2P(10, 11) L2P(12, 13) L2P(14, 15) L2P(16, 17) L2P(18, 19)
    L2P(20, 21) L2P(22, 23) L2P(24, 25) L2P(26, 27) L2P(28, 29)
    L2P(30, 31) L2P(32, 33) L2P(34, 35)

    float va = b4[0], vb = b4[0];
    L34P(0, 1)   L34P(2, 3)   L34P(4, 5)   L34P(6, 7)   L34P(8, 9)
    L34P(10, 11) L34P(12, 13) L34P(14, 15) L34P(16, 17) L34P(18, 19)
    L34P(20, 21) L34P(22, 23) L34P(24, 25) L34P(26, 27) L34P(28, 29)
    L34P(30, 31) L34P(32, 33) L34P(34, 35)

    // scatter-max on columns (row index irrelevant after the final row-max)
    const int2 p0 = ((const int2*)tidx)[k0];
    const int2 p1 = ((const int2*)tidx)[k0 + 1];
    atomicMax(&outU[p0.y], encodeF(va) - ENC_SENT);
    atomicMax(&outU[p1.y], encodeF(vb) - ENC_SENT);
}

__global__ __launch_bounds__(256) void init_kernel(unsigned* __restrict__ outU) {
    int gid = blockIdx.x * blockDim.x + threadIdx.x;
    if (gid < NCOLS) outU[gid] = 0u;   // == encode(SENTINEL) - bias
}

__global__ __launch_bounds__(256) void decode_kernel(unsigned* __restrict__ outU,
                                                     int out_size) {
    int gid = blockIdx.x * blockDim.x + threadIdx.x;
    if (gid < out_size) {
        float r = (gid < NCOLS) ? decodeF(outU[gid] + ENC_SENT) : 1.0f;
        ((float*)outU)[gid] = r;
    }
}

extern "C" void kernel_launch(void* const* d_in, const int* in_sizes, int n_in,
                              void* d_out, int out_size, void* d_ws, size_t ws_size,
                              hipStream_t stream) {
    const float* x    = (const float*)d_in[0];   // (1,4,1,K)
    const int*   tidx = (const int*)d_in[1];     // (K,2)
    const float* W1 = (const float*)d_in[2];
    const float* b1 = (const float*)d_in[3];
    const float* W2 = (const float*)d_in[4];
    const float* b2 = (const float*)d_in[5];
    const float* W3 = (const float*)d_in[6];
    const float* b3 = (const float*)d_in[7];
    const float* W4 = (const float*)d_in[8];
    const float* b4 = (const float*)d_in[9];
    unsigned* outU = (unsigned*)d_out;

    init_kernel<<<(NCOLS + 255) / 256, 256, 0, stream>>>(outU);

    const int nthreads = KN / 2;   // 2 elements per thread
    mlp_scatter_kernel<<<(nthreads + 255) / 256, 256, 0, stream>>>(
        x, tidx, W1, b1, W2, b2, W3, b3, W4, b4, outU);

    decode_kernel<<<(out_size + 255) / 256, 256, 0, stream>>>(outU, out_size);
}

// Round 8
// 140.996 us; speedup vs baseline: 2.7123x; 1.1661x over previous
//
#include <hip/hip_runtime.h>

#define KN 1000000
#define NCOLS 70400
#define NTILES (KN / 16)
#define NBLK 1024
#define NTHR 256

typedef _Float16 f16x8 __attribute__((ext_vector_type(8)));
typedef float    f32x4 __attribute__((ext_vector_type(4)));

// Order-preserving float<->uint encoding for atomicMax, biased so that
// encode(SENTINEL) == 0 -> zero-initialized slots decode to SENTINEL.
__device__ __forceinline__ unsigned encodeF(float f) {
    unsigned b = __float_as_uint(f);
    return (b & 0x80000000u) ? ~b : (b | 0x80000000u);
}
__device__ __forceinline__ float decodeF(unsigned e) {
    unsigned b = (e & 0x80000000u) ? (e & 0x7fffffffu) : ~e;
    return __uint_as_float(b);
}
#define ENC_SENT 0x34E76980u   // encodeF(-9999999.0f)

#define LGKM0() asm volatile("s_waitcnt lgkmcnt(0)" ::: "memory")

// MFMA 16x16x32 f16 layouts (gfx950, verified learn_hip m89/m120):
//   A[m][k]: m = lane&15, k = (lane>>4)*8 + j   (8 halfs / 4 VGPRs)
//   B[k][n]: n = lane&15, k = (lane>>4)*8 + j
//   D[m][n]: n = lane&15, m = (lane>>4)*4 + reg (4 floats)
// Arrangement: D(elem x out) = A(elem x in) * B(in x out);  B carries W^T,
// built once per wave and held in VGPRs (13 fragments = 52 VGPRs).
// Between layers the C-layout output round-trips through wave-private LDS
// to become the next A fragment. Row strides 40/72 halfs -> 2-way bank
// aliasing only (free per m136).

__global__ __launch_bounds__(NTHR)
__attribute__((amdgpu_waves_per_eu(4, 4)))
void mlp_scatter_mfma(const float* __restrict__ x, const int* __restrict__ tidx,
                      const float* __restrict__ W1, const float* __restrict__ b1,
                      const float* __restrict__ W2, const float* __restrict__ b2,
                      const float* __restrict__ W3, const float* __restrict__ b3,
                      const float* __restrict__ W4, const float* __restrict__ b4,
                      unsigned* __restrict__ outU)
{
    // per-wave region: H1 = halfs [0,640)   (16 rows x stride 40)
    //                  H2 = halfs [640,1792) (16 rows x stride 72)
    __shared__ _Float16 smem[4][1808];
    __shared__ float vt[4][16];

    const int lane = threadIdx.x & 63;
    const int wv   = threadIdx.x >> 6;
    const int quad = lane >> 4;
    const int n    = lane & 15;

    // zero the wave's staging (pads beyond k=47 in H2 must stay 0)
    {
        unsigned* sp = (unsigned*)&smem[wv][0];
#pragma unroll
        for (int i = 0; i < 14; ++i) sp[i * 64 + lane] = 0u;   // 896 dwords = 1792 halfs
    }

    // ---- build weight B-fragments (once per wave) ----
    auto bf = [&](const float* W, int OUT, int IN, int t, int ks) {
        f16x8 r;
#pragma unroll
        for (int j = 0; j < 8; ++j) {
            int k  = ks * 32 + quad * 8 + j;
            int ng = t * 16 + n;
            float w = (ng < OUT && k < IN) ? W[ng * IN + k] : 0.0f;
            r[j] = (_Float16)w;
        }
        return r;
    };
    const f16x8 B1_0 = bf(W1, 18,  4, 0, 0), B1_1 = bf(W1, 18,  4, 1, 0);
    const f16x8 B2_0 = bf(W2, 36, 18, 0, 0), B2_1 = bf(W2, 36, 18, 1, 0), B2_2 = bf(W2, 36, 18, 2, 0);
    const f16x8 B3_00 = bf(W3, 36, 36, 0, 0), B3_01 = bf(W3, 36, 36, 0, 1);
    const f16x8 B3_10 = bf(W3, 36, 36, 1, 0), B3_11 = bf(W3, 36, 36, 1, 1);
    const f16x8 B3_20 = bf(W3, 36, 36, 2, 0), B3_21 = bf(W3, 36, 36, 2, 1);
    const f16x8 B4_0 = bf(W4,  1, 36, 0, 0), B4_1 = bf(W4,  1, 36, 0, 1);

    // per-lane biases (pad outs get 0 -> relu(0+0)=0 keeps pads clean)
    const float bias1_0 = b1[n];
    const float bias1_1 = (n < 2) ? b1[16 + n] : 0.0f;
    const float bias2_0 = b2[n], bias2_1 = b2[16 + n];
    const float bias2_2 = (n < 4) ? b2[32 + n] : 0.0f;
    const float bias3_0 = b3[n], bias3_1 = b3[16 + n];
    const float bias3_2 = (n < 4) ? b3[32 + n] : 0.0f;
    const float b4s = b4[0];

    _Float16* H1 = &smem[wv][0];
    _Float16* H2 = &smem[wv][640];

    const int gw = (blockIdx.x * blockDim.x + threadIdx.x) >> 6;
    const int nw = (gridDim.x * blockDim.x) >> 6;

    for (int tile = gw; tile < NTILES; tile += nw) {
        const int kb = tile * 16;

        // layer-1 A fragment direct from global: k = quad*8+j, real only k<4
        const float xj0 = x[0 * KN + kb + n];
        const float xj1 = x[1 * KN + kb + n];
        const float xj2 = x[2 * KN + kb + n];
        const float xj3 = x[3 * KN + kb + n];
        f16x8 a1;
#pragma unroll
        for (int j = 0; j < 8; ++j) a1[j] = (_Float16)0.0f;
        if (quad == 0) {
            a1[0] = (_Float16)xj0; a1[1] = (_Float16)xj1;
            a1[2] = (_Float16)xj2; a1[3] = (_Float16)xj3;
        }

        const int col = ((const int2*)tidx)[kb + n].y;   // dup across quads

        // ---- L1: out 18 (2 tiles), K=32 (real 4) ----
        f32x4 c0 = {bias1_0, bias1_0, bias1_0, bias1_0};
        f32x4 c1 = {bias1_1, bias1_1, bias1_1, bias1_1};
        c0 = __builtin_amdgcn_mfma_f32_16x16x32_f16(a1, B1_0, c0, 0, 0, 0);
        c1 = __builtin_amdgcn_mfma_f32_16x16x32_f16(a1, B1_1, c1, 0, 0, 0);
#pragma unroll
        for (int r = 0; r < 4; ++r) {
            H1[(quad * 4 + r) * 40 + n]      = (_Float16)fmaxf(c0[r], 0.0f);
            H1[(quad * 4 + r) * 40 + 16 + n] = (_Float16)fmaxf(c1[r], 0.0f);
        }
        LGKM0();

        // ---- L2: out 36 (3 tiles), K=32 (real 18) ----
        const f16x8 a2 = *(const f16x8*)&H1[n * 40 + quad * 8];
        f32x4 d0 = {bias2_0, bias2_0, bias2_0, bias2_0};
        f32x4 d1 = {bias2_1, bias2_1, bias2_1, bias2_1};
        f32x4 d2 = {bias2_2, bias2_2, bias2_2, bias2_2};
        d0 = __builtin_amdgcn_mfma_f32_16x16x32_f16(a2, B2_0, d0, 0, 0, 0);
        d1 = __builtin_amdgcn_mfma_f32_16x16x32_f16(a2, B2_1, d1, 0, 0, 0);
        d2 = __builtin_amdgcn_mfma_f32_16x16x32_f16(a2, B2_2, d2, 0, 0, 0);
#pragma unroll
        for (int r = 0; r < 4; ++r) {
            H2[(quad * 4 + r) * 72 + n]      = (_Float16)fmaxf(d0[r], 0.0f);
            H2[(quad * 4 + r) * 72 + 16 + n] = (_Float16)fmaxf(d1[r], 0.0f);
            H2[(quad * 4 + r) * 72 + 32 + n] = (_Float16)fmaxf(d2[r], 0.0f);
        }
        LGKM0();

        // ---- L3: out 36 (3 tiles), K=64 (real 36, k48..63 perm-zero) ----
        const f16x8 a30 = *(const f16x8*)&H2[n * 72 + quad * 8];
        const f16x8 a31 = *(const f16x8*)&H2[n * 72 + 32 + quad * 8];
        f32x4 e0 = {bias3_0, bias3_0, bias3_0, bias3_0};
        f32x4 e1 = {bias3_1, bias3_1, bias3_1, bias3_1};
        f32x4 e2 = {bias3_2, bias3_2, bias3_2, bias3_2};
        e0 = __builtin_amdgcn_mfma_f32_16x16x32_f16(a30, B3_00, e0, 0, 0, 0);
        e0 = __builtin_amdgcn_mfma_f32_16x16x32_f16(a31, B3_01, e0, 0, 0, 0);
        e1 = __builtin_amdgcn_mfma_f32_16x16x32_f16(a30, B3_10, e1, 0, 0, 0);
        e1 = __builtin_amdgcn_mfma_f32_16x16x32_f16(a31, B3_11, e1, 0, 0, 0);
        e2 = __builtin_amdgcn_mfma_f32_16x16x32_f16(a30, B3_20, e2, 0, 0, 0);
        e2 = __builtin_amdgcn_mfma_f32_16x16x32_f16(a31, B3_21, e2, 0, 0, 0);
        LGKM0();   // a30/a31 consumed before overwrite (WAR)
#pragma unroll
        for (int r = 0; r < 4; ++r) {
            H2[(quad * 4 + r) * 72 + n]      = (_Float16)fmaxf(e0[r], 0.0f);
            H2[(quad * 4 + r) * 72 + 16 + n] = (_Float16)fmaxf(e1[r], 0.0f);
            H2[(quad * 4 + r) * 72 + 32 + n] = (_Float16)fmaxf(e2[r], 0.0f);
        }
        LGKM0();

        // ---- L4: out 1 (B4 col 0 only), K=64 ----
        const f16x8 a40 = *(const f16x8*)&H2[n * 72 + quad * 8];
        const f16x8 a41 = *(const f16x8*)&H2[n * 72 + 32 + quad * 8];
        f32x4 f0 = {0.0f, 0.0f, 0.0f, 0.0f};
        f0 = __builtin_amdgcn_mfma_f32_16x16x32_f16(a40, B4_0, f0, 0, 0, 0);
        f0 = __builtin_amdgcn_mfma_f32_16x16x32_f16(a41, B4_1, f0, 0, 0, 0);

        // v for elem m=quad*4+r lives in lanes n==0; exchange via vt
        if (n == 0) {
#pragma unroll
            for (int r = 0; r < 4; ++r) vt[wv][quad * 4 + r] = f0[r] + b4s;
        }
        LGKM0();   // cross-lane vt write -> read
        const float v = vt[wv][n];
        const unsigned enc = encodeF(v) - ENC_SENT;
        if (lane < 16) atomicMax(&outU[col], enc);
    }
}

__global__ __launch_bounds__(256) void init_kernel(unsigned* __restrict__ outU) {
    int gid = blockIdx.x * blockDim.x + threadIdx.x;
    if (gid < NCOLS) outU[gid] = 0u;   // == encode(SENTINEL) - bias
}

__global__ __launch_bounds__(256) void decode_kernel(unsigned* __restrict__ outU,
                                                     int out_size) {
    int gid = blockIdx.x * blockDim.x + threadIdx.x;
    if (gid < out_size) {
        float r = (gid < NCOLS) ? decodeF(outU[gid] + ENC_SENT) : 1.0f;
        ((float*)outU)[gid] = r;
    }
}

extern "C" void kernel_launch(void* const* d_in, const int* in_sizes, int n_in,
                              void* d_out, int out_size, void* d_ws, size_t ws_size,
                              hipStream_t stream) {
    const float* x    = (const float*)d_in[0];   // (1,4,1,K)
    const int*   tidx = (const int*)d_in[1];     // (K,2)
    const float* W1 = (const float*)d_in[2];
    const float* b1 = (const float*)d_in[3];
    const float* W2 = (const float*)d_in[4];
    const float* b2 = (const float*)d_in[5];
    const float* W3 = (const float*)d_in[6];
    const float* b3 = (const float*)d_in[7];
    const float* W4 = (const float*)d_in[8];
    const float* b4 = (const float*)d_in[9];
    unsigned* outU = (unsigned*)d_out;

    init_kernel<<<(NCOLS + 255) / 256, 256, 0, stream>>>(outU);

    mlp_scatter_mfma<<<NBLK, NTHR, 0, stream>>>(
        x, tidx, W1, b1, W2, b2, W3, b3, W4, b4, outU);

    decode_kernel<<<(out_size + 255) / 256, 256, 0, stream>>>(outU, out_size);
}

// Round 9
// 138.666 us; speedup vs baseline: 2.7579x; 1.0168x over previous
//
#include <hip/hip_runtime.h>

#define KN 1000000
#define NCOLS 70400
#define NPAIRS (KN / 32)          // 2 tiles (32 elems) per wave-iteration
#define NBLK 1024
#define NTHR 256

typedef _Float16 f16x8 __attribute__((ext_vector_type(8)));
typedef float    f32x4 __attribute__((ext_vector_type(4)));

__device__ __forceinline__ unsigned encodeF(float f) {
    unsigned b = __float_as_uint(f);
    return (b & 0x80000000u) ? ~b : (b | 0x80000000u);
}
__device__ __forceinline__ float decodeF(unsigned e) {
    unsigned b = (e & 0x80000000u) ? (e & 0x7fffffffu) : ~e;
    return __uint_as_float(b);
}
#define ENC_SENT 0x34E76980u   // encodeF(-9999999.0f)

#define MFMA16(a, b, c) __builtin_amdgcn_mfma_f32_16x16x32_f16((a), (b), (c), 0, 0, 0)

// MFMA 16x16x32 f16 layouts (gfx950): A[m][k]: m=lane&15, k=(lane>>4)*8+j;
// D[m][n]: n=lane&15, m=(lane>>4)*4+reg.  D(elem x out) = A(elem x in) * B(W^T).
// One aliased per-tile LDS buffer (16 rows x stride 72 halfs): L1 writes cols
// 0..31, L2 reads them then overwrites cols 0..47 (same-wave DS ops are
// hardware-in-order -> no manual waits). Cols 48..63 zeroed once (read by the
// k=32..63 A-frag; they multiply zero B-weights, zeroing only guards NaN junk).
// L4 (out=1) is a VALU dot + shfl_xor reduction -> no third LDS round trip.

__global__ __launch_bounds__(NTHR)
__attribute__((amdgpu_waves_per_eu(4, 4)))
void mlp_scatter_mfma(const float* __restrict__ x, const int* __restrict__ tidx,
                      const float* __restrict__ W1, const float* __restrict__ b1,
                      const float* __restrict__ W2, const float* __restrict__ b2,
                      const float* __restrict__ W3, const float* __restrict__ b3,
                      const float* __restrict__ W4, const float* __restrict__ b4,
                      unsigned* __restrict__ outU)
{
    __shared__ _Float16 smem[4][2][1152];   // 4 waves x 2 tiles x (16*72) halfs

    const int lane = threadIdx.x & 63;
    const int wv   = threadIdx.x >> 6;
    const int quad = lane >> 4;
    const int n    = lane & 15;

    _Float16* Ha = &smem[wv][0][0];
    _Float16* Hb = &smem[wv][1][0];

    // one-time zero of cols 48..63 (all 16 rows) in both buffers
    for (int i = lane; i < 128; i += 64) {
        const int row = i >> 3, dc = i & 7;
        ((unsigned*)(Ha + row * 72 + 48))[dc] = 0u;
        ((unsigned*)(Hb + row * 72 + 48))[dc] = 0u;
    }

    // ---- weight B-fragments, built once per wave ----
    auto bf = [&](const float* W, int OUT, int IN, int t, int ks) {
        f16x8 r;
#pragma unroll
        for (int j = 0; j < 8; ++j) {
            int k  = ks * 32 + quad * 8 + j;
            int ng = t * 16 + n;
            float w = (ng < OUT && k < IN) ? W[ng * IN + k] : 0.0f;
            r[j] = (_Float16)w;
        }
        return r;
    };
    const f16x8 B1_0 = bf(W1, 18,  4, 0, 0), B1_1 = bf(W1, 18,  4, 1, 0);
    const f16x8 B2_0 = bf(W2, 36, 18, 0, 0), B2_1 = bf(W2, 36, 18, 1, 0), B2_2 = bf(W2, 36, 18, 2, 0);
    const f16x8 B3_00 = bf(W3, 36, 36, 0, 0), B3_01 = bf(W3, 36, 36, 0, 1);
    const f16x8 B3_10 = bf(W3, 36, 36, 1, 0), B3_11 = bf(W3, 36, 36, 1, 1);
    const f16x8 B3_20 = bf(W3, 36, 36, 2, 0), B3_21 = bf(W3, 36, 36, 2, 1);

    const float bias1_0 = b1[n];
    const float bias1_1 = (n < 2) ? b1[16 + n] : 0.0f;
    const float bias2_0 = b2[n], bias2_1 = b2[16 + n];
    const float bias2_2 = (n < 4) ? b2[32 + n] : 0.0f;
    const float bias3_0 = b3[n], bias3_1 = b3[16 + n];
    const float bias3_2 = (n < 4) ? b3[32 + n] : 0.0f;
    const float b4s = b4[0];
    // per-lane W4 slices for the VALU L4 dot
    const float w4_0 = W4[n], w4_1 = W4[16 + n];
    const float w4_2 = (n < 4) ? W4[32 + n] : 0.0f;

    const int gw = (blockIdx.x * blockDim.x + threadIdx.x) >> 6;
    const int nw = (gridDim.x * blockDim.x) >> 6;

    // ---- prefetch-rotate state for pair p ----
    float cxa0, cxa1, cxa2, cxa3, cxb0, cxb1, cxb2, cxb3;
    int cca = 0, ccb = 0;
    if (gw < NPAIRS) {
        const int kb = gw * 32;
        cxa0 = x[0 * KN + kb + n];      cxb0 = x[0 * KN + kb + 16 + n];
        cxa1 = x[1 * KN + kb + n];      cxb1 = x[1 * KN + kb + 16 + n];
        cxa2 = x[2 * KN + kb + n];      cxb2 = x[2 * KN + kb + 16 + n];
        cxa3 = x[3 * KN + kb + n];      cxb3 = x[3 * KN + kb + 16 + n];
        cca  = tidx[2 * (kb + n) + 1];  ccb  = tidx[2 * (kb + 16 + n) + 1];
    }

    for (int p = gw; p < NPAIRS; ) {
        const int pn = p + nw;
        // working copies of current pair
        const float xa0 = cxa0, xa1 = cxa1, xa2 = cxa2, xa3 = cxa3;
        const float xb0 = cxb0, xb1 = cxb1, xb2 = cxb2, xb3 = cxb3;
        const int cola = cca, colb = ccb;
        // issue next pair's loads (wave-uniform branch)
        if (pn < NPAIRS) {
            const int kb = pn * 32;
            cxa0 = x[0 * KN + kb + n];      cxb0 = x[0 * KN + kb + 16 + n];
            cxa1 = x[1 * KN + kb + n];      cxb1 = x[1 * KN + kb + 16 + n];
            cxa2 = x[2 * KN + kb + n];      cxb2 = x[2 * KN + kb + 16 + n];
            cxa3 = x[3 * KN + kb + n];      cxb3 = x[3 * KN + kb + 16 + n];
            cca  = tidx[2 * (kb + n) + 1];  ccb  = tidx[2 * (kb + 16 + n) + 1];
        }

        // ---- L1: A-frags direct from x (real k<4, quad 0 only) ----
        f16x8 a1a = {}, a1b = {};
        if (quad == 0) {
            a1a[0] = (_Float16)xa0; a1a[1] = (_Float16)xa1;
            a1a[2] = (_Float16)xa2; a1a[3] = (_Float16)xa3;
            a1b[0] = (_Float16)xb0; a1b[1] = (_Float16)xb1;
            a1b[2] = (_Float16)xb2; a1b[3] = (_Float16)xb3;
        }
        f32x4 c0a = {bias1_0, bias1_0, bias1_0, bias1_0};
        f32x4 c1a = {bias1_1, bias1_1, bias1_1, bias1_1};
        f32x4 c0b = c0a, c1b = c1a;
        c0a = MFMA16(a1a, B1_0, c0a);  c0b = MFMA16(a1b, B1_0, c0b);
        c1a = MFMA16(a1a, B1_1, c1a);  c1b = MFMA16(a1b, B1_1, c1b);
#pragma unroll
        for (int r = 0; r < 4; ++r) {
            const int row = (quad * 4 + r) * 72;
            Ha[row + n]      = (_Float16)fmaxf(c0a[r], 0.0f);
            Ha[row + 16 + n] = (_Float16)fmaxf(c1a[r], 0.0f);
            Hb[row + n]      = (_Float16)fmaxf(c0b[r], 0.0f);
            Hb[row + 16 + n] = (_Float16)fmaxf(c1b[r], 0.0f);
        }

        // ---- L2: read A (k 0..31), 3 MFMA per tile, overwrite cols 0..47 ----
        const f16x8 a2a = *(const f16x8*)&Ha[n * 72 + quad * 8];
        const f16x8 a2b = *(const f16x8*)&Hb[n * 72 + quad * 8];
        f32x4 d0a = {bias2_0, bias2_0, bias2_0, bias2_0};
        f32x4 d1a = {bias2_1, bias2_1, bias2_1, bias2_1};
        f32x4 d2a = {bias2_2, bias2_2, bias2_2, bias2_2};
        f32x4 d0b = d0a, d1b = d1a, d2b = d2a;
        d0a = MFMA16(a2a, B2_0, d0a);  d0b = MFMA16(a2b, B2_0, d0b);
        d1a = MFMA16(a2a, B2_1, d1a);  d1b = MFMA16(a2b, B2_1, d1b);
        d2a = MFMA16(a2a, B2_2, d2a);  d2b = MFMA16(a2b, B2_2, d2b);
#pragma unroll
        for (int r = 0; r < 4; ++r) {
            const int row = (quad * 4 + r) * 72;
            Ha[row + n]      = (_Float16)fmaxf(d0a[r], 0.0f);
            Ha[row + 16 + n] = (_Float16)fmaxf(d1a[r], 0.0f);
            Ha[row + 32 + n] = (_Float16)fmaxf(d2a[r], 0.0f);
            Hb[row + n]      = (_Float16)fmaxf(d0b[r], 0.0f);
            Hb[row + 16 + n] = (_Float16)fmaxf(d1b[r], 0.0f);
            Hb[row + 32 + n] = (_Float16)fmaxf(d2b[r], 0.0f);
        }

        // ---- L3: 6 MFMA per tile (k real 36; k>=36 B-weights are zero) ----
        const f16x8 a30a = *(const f16x8*)&Ha[n * 72 + quad * 8];
        const f16x8 a31a = *(const f16x8*)&Ha[n * 72 + 32 + quad * 8];
        const f16x8 a30b = *(const f16x8*)&Hb[n * 72 + quad * 8];
        const f16x8 a31b = *(const f16x8*)&Hb[n * 72 + 32 + quad * 8];
        f32x4 e0a = {bias3_0, bias3_0, bias3_0, bias3_0};
        f32x4 e1a = {bias3_1, bias3_1, bias3_1, bias3_1};
        f32x4 e2a = {bias3_2, bias3_2, bias3_2, bias3_2};
        f32x4 e0b = e0a, e1b = e1a, e2b = e2a;
        e0a = MFMA16(a30a, B3_00, e0a);  e0a = MFMA16(a31a, B3_01, e0a);
        e1a = MFMA16(a30a, B3_10, e1a);  e1a = MFMA16(a31a, B3_11, e1a);
        e2a = MFMA16(a30a, B3_20, e2a);  e2a = MFMA16(a31a, B3_21, e2a);
        e0b = MFMA16(a30b, B3_00, e0b);  e0b = MFMA16(a31b, B3_01, e0b);
        e1b = MFMA16(a30b, B3_10, e1b);  e1b = MFMA16(a31b, B3_11, e1b);
        e2b = MFMA16(a30b, B3_20, e2b);  e2b = MFMA16(a31b, B3_21, e2b);

        // ---- L4 in VALU: v[elem] = sum_out W4[out]*relu(h3[elem][out]) ----
        float pa[4], pb[4];
#pragma unroll
        for (int r = 0; r < 4; ++r) {
            pa[r] = fmaf(w4_0, fmaxf(e0a[r], 0.0f),
                    fmaf(w4_1, fmaxf(e1a[r], 0.0f),
                         w4_2 * fmaxf(e2a[r], 0.0f)));
            pb[r] = fmaf(w4_0, fmaxf(e0b[r], 0.0f),
                    fmaf(w4_1, fmaxf(e1b[r], 0.0f),
                         w4_2 * fmaxf(e2b[r], 0.0f)));
        }
        // reduce across the 16 n-lanes within each quad segment
#pragma unroll
        for (int m = 8; m >= 1; m >>= 1) {
#pragma unroll
            for (int r = 0; r < 4; ++r) {
                pa[r] += __shfl_xor(pa[r], m, 16);
                pb[r] += __shfl_xor(pb[r], m, 16);
            }
        }
        // elem = quad*4 + r; the lane with n == elem (i.e. n>>2 == quad) owns
        // that elem's col and fires the atomic.
        if ((n >> 2) == quad) {
            const int r = n & 3;
            atomicMax(&outU[cola], encodeF(pa[r] + b4s) - ENC_SENT);
            atomicMax(&outU[colb], encodeF(pb[r] + b4s) - ENC_SENT);
        }

        p = pn;
    }
}

__global__ __launch_bounds__(256) void init_kernel(unsigned* __restrict__ outU) {
    int gid = blockIdx.x * blockDim.x + threadIdx.x;
    if (gid < NCOLS) outU[gid] = 0u;   // == encode(SENTINEL) - bias
}

__global__ __launch_bounds__(256) void decode_kernel(unsigned* __restrict__ outU,
                                                     int out_size) {
    int gid = blockIdx.x * blockDim.x + threadIdx.x;
    if (gid < out_size) {
        float r = (gid < NCOLS) ? decodeF(outU[gid] + ENC_SENT) : 1.0f;
        ((float*)outU)[gid] = r;
    }
}

extern "C" void kernel_launch(void* const* d_in, const int* in_sizes, int n_in,
                              void* d_out, int out_size, void* d_ws, size_t ws_size,
                              hipStream_t stream) {
    const float* x    = (const float*)d_in[0];   // (1,4,1,K)
    const int*   tidx = (const int*)d_in[1];     // (K,2)
    const float* W1 = (const float*)d_in[2];
    const float* b1 = (const float*)d_in[3];
    const float* W2 = (const float*)d_in[4];
    const float* b2 = (const float*)d_in[5];
    const float* W3 = (const float*)d_in[6];
    const float* b3 = (const float*)d_in[7];
    const float* W4 = (const float*)d_in[8];
    const float* b4 = (const float*)d_in[9];
    unsigned* outU = (unsigned*)d_out;

    init_kernel<<<(NCOLS + 255) / 256, 256, 0, stream>>>(outU);

    mlp_scatter_mfma<<<NBLK, NTHR, 0, stream>>>(
        x, tidx, W1, b1, W2, b2, W3, b3, W4, b4, outU);

    decode_kernel<<<(out_size + 255) / 256, 256, 0, stream>>>(outU, out_size);
}

// Round 10
// 133.661 us; speedup vs baseline: 2.8612x; 1.0374x over previous
//
#include <hip/hip_runtime.h>

#define KN 1000000
#define NCOLS 70400
#define NPAIRS (KN / 32)          // 2 tiles (32 elems) per wave-iteration
#define NBLK 1024
#define NTHR 256

typedef _Float16 f16x8 __attribute__((ext_vector_type(8)));
typedef float    f32x4 __attribute__((ext_vector_type(4)));

__device__ __forceinline__ unsigned encodeF(float f) {
    unsigned b = __float_as_uint(f);
    return (b & 0x80000000u) ? ~b : (b | 0x80000000u);
}
__device__ __forceinline__ float decodeF(unsigned e) {
    unsigned b = (e & 0x80000000u) ? (e & 0x7fffffffu) : ~e;
    return __uint_as_float(b);
}
#define ENC_SENT 0x34E76980u   // encodeF(-9999999.0f)

#define MFMA16(a, b, c) __builtin_amdgcn_mfma_f32_16x16x32_f16((a), (b), (c), 0, 0, 0)

// LDS layout of raw fp32 weights (staged coalesced once per block):
#define OW1 0
#define OB1 72
#define OW2 90
#define OB2 738
#define OW3 774
#define OB3 2070
#define OW4 2106
#define OB4 2142
#define NWTS 2143

// MFMA 16x16x32 f16 layouts (gfx950): A[m][k]: m=lane&15, k=(lane>>4)*8+j;
// D[m][n]: n=lane&15, m=(lane>>4)*4+reg.  D(elem x out) = A(elem x in) * B(W^T).
// R10: B-fragments are built from LDS-staged weights (ds gathers) instead of
// divergent global gathers — R8/R9's invariant ~58us was TA address-processing
// cost of ~104 x 64-lane scattered global loads per wave (setup-dominated at
// only ~7.6 loop iterations/wave).

__global__ __launch_bounds__(NTHR)
__attribute__((amdgpu_waves_per_eu(4, 4)))
void mlp_scatter_mfma(const float* __restrict__ x, const int* __restrict__ tidx,
                      const float* __restrict__ W1, const float* __restrict__ b1,
                      const float* __restrict__ W2, const float* __restrict__ b2,
                      const float* __restrict__ W3, const float* __restrict__ b3,
                      const float* __restrict__ W4, const float* __restrict__ b4,
                      unsigned* __restrict__ outU)
{
    __shared__ float    sw[NWTS];           // raw fp32 weights, block-shared
    __shared__ _Float16 smem[4][2][1152];   // 4 waves x 2 tiles x (16*72) halfs

    const int t    = threadIdx.x;
    const int lane = t & 63;
    const int wv   = t >> 6;
    const int quad = lane >> 4;
    const int n    = lane & 15;

    // ---- coalesced one-time stage of all weights into LDS ----
    for (int i = t; i < 72;   i += NTHR) sw[OW1 + i] = W1[i];
    for (int i = t; i < 18;   i += NTHR) sw[OB1 + i] = b1[i];
    for (int i = t; i < 648;  i += NTHR) sw[OW2 + i] = W2[i];
    for (int i = t; i < 36;   i += NTHR) sw[OB2 + i] = b2[i];
    for (int i = t; i < 1296; i += NTHR) sw[OW3 + i] = W3[i];
    for (int i = t; i < 36;   i += NTHR) sw[OB3 + i] = b3[i];
    for (int i = t; i < 36;   i += NTHR) sw[OW4 + i] = W4[i];
    if (t == 0) sw[OB4] = b4[0];

    _Float16* Ha = &smem[wv][0][0];
    _Float16* Hb = &smem[wv][1][0];

    // one-time zero of cols 48..63 (all 16 rows) in both tile buffers
    for (int i = lane; i < 128; i += 64) {
        const int row = i >> 3, dc = i & 7;
        ((unsigned*)(Ha + row * 72 + 48))[dc] = 0u;
        ((unsigned*)(Hb + row * 72 + 48))[dc] = 0u;
    }
    __syncthreads();

    // ---- weight B-fragments, built once per wave from LDS (no TA cost) ----
    auto bf = [&](int off, int OUT, int IN, int tt, int ks) {
        f16x8 r;
#pragma unroll
        for (int j = 0; j < 8; ++j) {
            int k  = ks * 32 + quad * 8 + j;
            int ng = tt * 16 + n;
            float w = (ng < OUT && k < IN) ? sw[off + ng * IN + k] : 0.0f;
            r[j] = (_Float16)w;
        }
        return r;
    };
    const f16x8 B1_0 = bf(OW1, 18,  4, 0, 0), B1_1 = bf(OW1, 18,  4, 1, 0);
    const f16x8 B2_0 = bf(OW2, 36, 18, 0, 0), B2_1 = bf(OW2, 36, 18, 1, 0), B2_2 = bf(OW2, 36, 18, 2, 0);
    const f16x8 B3_00 = bf(OW3, 36, 36, 0, 0), B3_01 = bf(OW3, 36, 36, 0, 1);
    const f16x8 B3_10 = bf(OW3, 36, 36, 1, 0), B3_11 = bf(OW3, 36, 36, 1, 1);
    const f16x8 B3_20 = bf(OW3, 36, 36, 2, 0), B3_21 = bf(OW3, 36, 36, 2, 1);

    const float bias1_0 = sw[OB1 + n];
    const float bias1_1 = (n < 2) ? sw[OB1 + 16 + n] : 0.0f;
    const float bias2_0 = sw[OB2 + n], bias2_1 = sw[OB2 + 16 + n];
    const float bias2_2 = (n < 4) ? sw[OB2 + 32 + n] : 0.0f;
    const float bias3_0 = sw[OB3 + n], bias3_1 = sw[OB3 + 16 + n];
    const float bias3_2 = (n < 4) ? sw[OB3 + 32 + n] : 0.0f;
    const float b4s = sw[OB4];
    const float w4_0 = sw[OW4 + n], w4_1 = sw[OW4 + 16 + n];
    const float w4_2 = (n < 4) ? sw[OW4 + 32 + n] : 0.0f;

    const int gw = (blockIdx.x * blockDim.x + t) >> 6;
    const int nw = (gridDim.x * blockDim.x) >> 6;

    // ---- prefetch-rotate state for pair p ----
    float cxa0, cxa1, cxa2, cxa3, cxb0, cxb1, cxb2, cxb3;
    int cca = 0, ccb = 0;
    if (gw < NPAIRS) {
        const int kb = gw * 32;
        cxa0 = x[0 * KN + kb + n];      cxb0 = x[0 * KN + kb + 16 + n];
        cxa1 = x[1 * KN + kb + n];      cxb1 = x[1 * KN + kb + 16 + n];
        cxa2 = x[2 * KN + kb + n];      cxb2 = x[2 * KN + kb + 16 + n];
        cxa3 = x[3 * KN + kb + n];      cxb3 = x[3 * KN + kb + 16 + n];
        cca  = tidx[2 * (kb + n) + 1];  ccb  = tidx[2 * (kb + 16 + n) + 1];
    }

    for (int p = gw; p < NPAIRS; ) {
        const int pn = p + nw;
        const float xa0 = cxa0, xa1 = cxa1, xa2 = cxa2, xa3 = cxa3;
        const float xb0 = cxb0, xb1 = cxb1, xb2 = cxb2, xb3 = cxb3;
        const int cola = cca, colb = ccb;
        if (pn < NPAIRS) {
            const int kb = pn * 32;
            cxa0 = x[0 * KN + kb + n];      cxb0 = x[0 * KN + kb + 16 + n];
            cxa1 = x[1 * KN + kb + n];      cxb1 = x[1 * KN + kb + 16 + n];
            cxa2 = x[2 * KN + kb + n];      cxb2 = x[2 * KN + kb + 16 + n];
            cxa3 = x[3 * KN + kb + n];      cxb3 = x[3 * KN + kb + 16 + n];
            cca  = tidx[2 * (kb + n) + 1];  ccb  = tidx[2 * (kb + 16 + n) + 1];
        }

        // ---- L1: A-frags direct from x (real k<4, quad 0 only) ----
        f16x8 a1a = {}, a1b = {};
        if (quad == 0) {
            a1a[0] = (_Float16)xa0; a1a[1] = (_Float16)xa1;
            a1a[2] = (_Float16)xa2; a1a[3] = (_Float16)xa3;
            a1b[0] = (_Float16)xb0; a1b[1] = (_Float16)xb1;
            a1b[2] = (_Float16)xb2; a1b[3] = (_Float16)xb3;
        }
        f32x4 c0a = {bias1_0, bias1_0, bias1_0, bias1_0};
        f32x4 c1a = {bias1_1, bias1_1, bias1_1, bias1_1};
        f32x4 c0b = c0a, c1b = c1a;
        c0a = MFMA16(a1a, B1_0, c0a);  c0b = MFMA16(a1b, B1_0, c0b);
        c1a = MFMA16(a1a, B1_1, c1a);  c1b = MFMA16(a1b, B1_1, c1b);
#pragma unroll
        for (int r = 0; r < 4; ++r) {
            const int row = (quad * 4 + r) * 72;
            Ha[row + n]      = (_Float16)fmaxf(c0a[r], 0.0f);
            Ha[row + 16 + n] = (_Float16)fmaxf(c1a[r], 0.0f);
            Hb[row + n]      = (_Float16)fmaxf(c0b[r], 0.0f);
            Hb[row + 16 + n] = (_Float16)fmaxf(c1b[r], 0.0f);
        }

        // ---- L2: read A (k 0..31), 3 MFMA per tile, overwrite cols 0..47 ----
        const f16x8 a2a = *(const f16x8*)&Ha[n * 72 + quad * 8];
        const f16x8 a2b = *(const f16x8*)&Hb[n * 72 + quad * 8];
        f32x4 d0a = {bias2_0, bias2_0, bias2_0, bias2_0};
        f32x4 d1a = {bias2_1, bias2_1, bias2_1, bias2_1};
        f32x4 d2a = {bias2_2, bias2_2, bias2_2, bias2_2};
        f32x4 d0b = d0a, d1b = d1a, d2b = d2a;
        d0a = MFMA16(a2a, B2_0, d0a);  d0b = MFMA16(a2b, B2_0, d0b);
        d1a = MFMA16(a2a, B2_1, d1a);  d1b = MFMA16(a2b, B2_1, d1b);
        d2a = MFMA16(a2a, B2_2, d2a);  d2b = MFMA16(a2b, B2_2, d2b);
#pragma unroll
        for (int r = 0; r < 4; ++r) {
            const int row = (quad * 4 + r) * 72;
            Ha[row + n]      = (_Float16)fmaxf(d0a[r], 0.0f);
            Ha[row + 16 + n] = (_Float16)fmaxf(d1a[r], 0.0f);
            Ha[row + 32 + n] = (_Float16)fmaxf(d2a[r], 0.0f);
            Hb[row + n]      = (_Float16)fmaxf(d0b[r], 0.0f);
            Hb[row + 16 + n] = (_Float16)fmaxf(d1b[r], 0.0f);
            Hb[row + 32 + n] = (_Float16)fmaxf(d2b[r], 0.0f);
        }

        // ---- L3: 6 MFMA per tile (k real 36; k>=36 B-weights are zero) ----
        const f16x8 a30a = *(const f16x8*)&Ha[n * 72 + quad * 8];
        const f16x8 a31a = *(const f16x8*)&Ha[n * 72 + 32 + quad * 8];
        const f16x8 a30b = *(const f16x8*)&Hb[n * 72 + quad * 8];
        const f16x8 a31b = *(const f16x8*)&Hb[n * 72 + 32 + quad * 8];
        f32x4 e0a = {bias3_0, bias3_0, bias3_0, bias3_0};
        f32x4 e1a = {bias3_1, bias3_1, bias3_1, bias3_1};
        f32x4 e2a = {bias3_2, bias3_2, bias3_2, bias3_2};
        f32x4 e0b = e0a, e1b = e1a, e2b = e2a;
        e0a = MFMA16(a30a, B3_00, e0a);  e0a = MFMA16(a31a, B3_01, e0a);
        e1a = MFMA16(a30a, B3_10, e1a);  e1a = MFMA16(a31a, B3_11, e1a);
        e2a = MFMA16(a30a, B3_20, e2a);  e2a = MFMA16(a31a, B3_21, e2a);
        e0b = MFMA16(a30b, B3_00, e0b);  e0b = MFMA16(a31b, B3_01, e0b);
        e1b = MFMA16(a30b, B3_10, e1b);  e1b = MFMA16(a31b, B3_11, e1b);
        e2b = MFMA16(a30b, B3_20, e2b);  e2b = MFMA16(a31b, B3_21, e2b);

        // ---- L4 in VALU: v[elem] = sum_out W4[out]*relu(h3[elem][out]) ----
        float pa[4], pb[4];
#pragma unroll
        for (int r = 0; r < 4; ++r) {
            pa[r] = fmaf(w4_0, fmaxf(e0a[r], 0.0f),
                    fmaf(w4_1, fmaxf(e1a[r], 0.0f),
                         w4_2 * fmaxf(e2a[r], 0.0f)));
            pb[r] = fmaf(w4_0, fmaxf(e0b[r], 0.0f),
                    fmaf(w4_1, fmaxf(e1b[r], 0.0f),
                         w4_2 * fmaxf(e2b[r], 0.0f)));
        }
#pragma unroll
        for (int m = 8; m >= 1; m >>= 1) {
#pragma unroll
            for (int r = 0; r < 4; ++r) {
                pa[r] += __shfl_xor(pa[r], m, 16);
                pb[r] += __shfl_xor(pb[r], m, 16);
            }
        }
        if ((n >> 2) == quad) {
            const int r = n & 3;
            atomicMax(&outU[cola], encodeF(pa[r] + b4s) - ENC_SENT);
            atomicMax(&outU[colb], encodeF(pb[r] + b4s) - ENC_SENT);
        }

        p = pn;
    }
}

__global__ __launch_bounds__(256) void init_kernel(unsigned* __restrict__ outU) {
    int gid = blockIdx.x * blockDim.x + threadIdx.x;
    if (gid < NCOLS) outU[gid] = 0u;   // == encode(SENTINEL) - bias
}

__global__ __launch_bounds__(256) void decode_kernel(unsigned* __restrict__ outU,
                                                     int out_size) {
    int gid = blockIdx.x * blockDim.x + threadIdx.x;
    if (gid < out_size) {
        float r = (gid < NCOLS) ? decodeF(outU[gid] + ENC_SENT) : 1.0f;
        ((float*)outU)[gid] = r;
    }
}

extern "C" void kernel_launch(void* const* d_in, const int* in_sizes, int n_in,
                              void* d_out, int out_size, void* d_ws, size_t ws_size,
                              hipStream_t stream) {
    const float* x    = (const float*)d_in[0];   // (1,4,1,K)
    const int*   tidx = (const int*)d_in[1];     // (K,2)
    const float* W1 = (const float*)d_in[2];
    const float* b1 = (const float*)d_in[3];
    const float* W2 = (const float*)d_in[4];
    const float* b2 = (const float*)d_in[5];
    const float* W3 = (const float*)d_in[6];
    const float* b3 = (const float*)d_in[7];
    const float* W4 = (const float*)d_in[8];
    const float* b4 = (const float*)d_in[9];
    unsigned* outU = (unsigned*)d_out;

    init_kernel<<<(NCOLS + 255) / 256, 256, 0, stream>>>(outU);

    mlp_scatter_mfma<<<NBLK, NTHR, 0, stream>>>(
        x, tidx, W1, b1, W2, b2, W3, b3, W4, b4, outU);

    decode_kernel<<<(out_size + 255) / 256, 256, 0, stream>>>(outU, out_size);
}